// Round 9
// baseline (450.612 us; speedup 1.0000x reference)
//
#include <hip/hip_runtime.h>

// Problem constants (fixed by setup_inputs)
#define T_LEN 128
#define NB_BINS 15

// ---------------------------------------------------------------------------
// DIAGNOSTIC ROUND: R3's fused kernel body executed 3x inside one dispatch
// (rep 0 -> real outputs, reps 1-2 -> d_ws dummies). Purpose: dispatch dur
// ~490us exceeds the harness's 2.1GB poison fills (~320us) so THIS kernel
// finally surfaces in the top-5 rocprof rows with FETCH/WRITE/VALU/Occupancy.
// Per-pass timing already calibrated by R7's slope experiment: 166.4us.
// ---------------------------------------------------------------------------
__global__ __launch_bounds__(256) void k_fused3(
    const float4* __restrict__ S4,
    const float4* __restrict__ Y4,
    const float4* __restrict__ M4,
    const float4* __restrict__ C4,
    const float4* __restrict__ L4,
    const float4* __restrict__ wgd4,
    const float4* __restrict__ wbd4,
    const float4* __restrict__ wgs4,
    const float4* __restrict__ wbs4,
    const float*  __restrict__ p_psi,
    const float*  __restrict__ p_gA,
    const float*  __restrict__ p_lsz,
    const float*  __restrict__ p_b0,
    const float*  __restrict__ p_bZ,
    const float*  __restrict__ p_bbins,
    const float*  __restrict__ p_bT,
    float* zf0, float* zv0, float* ll0,
    float* zf1, float* zv1, float* ll1)
{
    __shared__ float sbins[NB_BINS];
    if (threadIdx.x < NB_BINS) sbins[threadIdx.x] = p_bbins[threadIdx.x];
    __syncthreads();

    const int gtid = blockIdx.x * blockDim.x + threadIdx.x;
    const int n = gtid >> 2;     // sequence index
    const int s = gtid & 3;      // sublane within 4-lane group

    // per-lane slices of the dynamic weights (dense L layout):
    // lane s covers elements [4s,4s+4) and [16+4s,16+4s+4)
    const float4 wga = wgd4[s],     wgb = wgd4[s + 4];
    const float4 wba = wbd4[s],     wbb = wbd4[s + 4];

    const float psi  = p_psi[0];
    const float gA   = p_gA[0];
    const float e    = __expf(p_lsz[0]);
    const float sig2 = e * e;
    const float b0   = p_b0[0];
    const float bZ   = p_bZ[0];
    const float bT30 = p_bT[0] * (1.0f / 30.0f);
    const float psi2 = psi * psi;
    const float bZ2  = bZ * bZ;

    // static dots: each lane 4 elems of 16, butterfly over the 4-lane group
    float gs, bs;
    {
        const float4 c  = C4[n * 4 + s];
        const float4 wg = wgs4[s];
        const float4 wb = wbs4[s];
        gs = c.x * wg.x + c.y * wg.y + c.z * wg.z + c.w * wg.w;
        bs = c.x * wb.x + c.y * wb.y + c.z * wb.z + c.w * wb.w;
        gs += __shfl_xor(gs, 1, 64); gs += __shfl_xor(gs, 2, 64);
        bs += __shfl_xor(bs, 1, 64); bs += __shfl_xor(bs, 2, 64);
    }

    const size_t lb  = (size_t)n * T_LEN * 8;
    const int    sbi = n * (T_LEN / 4);

#define STEP(J, LA, LB, SS, YY, MM, PMOUT, PVOUT, PROBOUT) do {               \
        const float s_v = (SS), y_v = (YY), m_v = (MM);                       \
        float g   = LA.x*wga.x + LA.y*wga.y + LA.z*wga.z + LA.w*wga.w         \
                  + LB.x*wgb.x + LB.y*wgb.y + LB.z*wgb.z + LB.w*wgb.w;        \
        float bdv = LA.x*wba.x + LA.y*wba.y + LA.z*wba.z + LA.w*wba.w         \
                  + LB.x*wbb.x + LB.y*wbb.y + LB.z*wbb.z + LB.w*wbb.w;        \
        g   += __shfl_xor(g,   1, 64); g   += __shfl_xor(g,   2, 64);         \
        bdv += __shfl_xor(bdv, 1, 64); bdv += __shfl_xor(bdv, 2, 64);         \
        int cnt = (int)fmaxf(0.0f, fminf(14.0f,                               \
                      ceilf(fmaf(s_v, 3.0f, 7.5f)) - 1.0f));                  \
        const float be    = sbins[cnt];                                       \
        const float zpm   = psi * zm + gA * s_v + g + gs;                     \
        const float zpv   = psi2 * zvv + sig2;                                \
        float logit = b0 + bZ * zpm + be + bdv + bs                           \
                    + bT30 * (float)(4 * k + (J));                            \
        logit = fminf(fmaxf(logit, -20.0f), 20.0f);                           \
        const float prob  = __builtin_amdgcn_rcpf(1.0f + __expf(-logit));     \
        const float grad  = (y_v - prob) * bZ * m_v;                          \
        const float hess  = bZ2 * prob * (1.0f - prob) * m_v + 1e-6f;         \
        const float pvv   = __builtin_amdgcn_rcpf(                            \
                   __builtin_amdgcn_rcpf(zpv + 1e-8f) + hess);                \
        const float pmm   = zpm + pvv * grad;                                 \
        zm = pmm; zvv = pvv; PMOUT = pmm; PVOUT = pvv; PROBOUT = prob;        \
    } while (0)

    #pragma clang loop unroll(disable)
    for (int rep = 0; rep < 3; ++rep) {
        float* zf  = (rep == 0) ? zf0 : zf1;
        float* zv  = (rep == 0) ? zv0 : zv1;
        float* llp = (rep == 0) ? ll0 : ll1;

        // ---- chunk 0 load ----
        float4 Lc0 = L4[lb + 0*8 + s], Lc1 = L4[lb + 0*8 + 4 + s];
        float4 Lc2 = L4[lb + 1*8 + s], Lc3 = L4[lb + 1*8 + 4 + s];
        float4 Lc4 = L4[lb + 2*8 + s], Lc5 = L4[lb + 2*8 + 4 + s];
        float4 Lc6 = L4[lb + 3*8 + s], Lc7 = L4[lb + 3*8 + 4 + s];
        float4 sc = S4[sbi], yc = Y4[sbi], mc = M4[sbi];

        float zm = 0.0f, zvv = 1.0f, ll = 0.0f;

        for (int k = 0; k < T_LEN / 4; ++k) {
            const int kn = (k + 1 < T_LEN / 4) ? (k + 1) : k;
            const size_t lbn = lb + (size_t)(4 * kn) * 8;
            float4 Ln0 = L4[lbn + 0*8 + s], Ln1 = L4[lbn + 0*8 + 4 + s];
            float4 Ln2 = L4[lbn + 1*8 + s], Ln3 = L4[lbn + 1*8 + 4 + s];
            float4 Ln4 = L4[lbn + 2*8 + s], Ln5 = L4[lbn + 2*8 + 4 + s];
            float4 Ln6 = L4[lbn + 3*8 + s], Ln7 = L4[lbn + 3*8 + 4 + s];
            float4 snn = S4[sbi + kn], ynn = Y4[sbi + kn], mnn = M4[sbi + kn];

            float pm0, pm1, pm2, pm3, pv0, pv1, pv2, pv3, pr0, pr1, pr2, pr3;
            STEP(0, Lc0, Lc1, sc.x, yc.x, mc.x, pm0, pv0, pr0);
            STEP(1, Lc2, Lc3, sc.y, yc.y, mc.y, pm1, pv1, pr1);
            STEP(2, Lc4, Lc5, sc.z, yc.z, mc.z, pm2, pv2, pr2);
            STEP(3, Lc6, Lc7, sc.w, yc.w, mc.w, pm3, pv3, pr3);

            const float pmsel = (s == 0) ? pm0 : (s == 1) ? pm1 : (s == 2) ? pm2 : pm3;
            const float pvsel = (s == 0) ? pv0 : (s == 1) ? pv1 : (s == 2) ? pv2 : pv3;
            const size_t oidx = (size_t)n * T_LEN + 4 * k + s;
            zf[oidx] = pmsel;
            zv[oidx] = pvsel;

            {
                const float prs = (s == 0) ? pr0 : (s == 1) ? pr1 : (s == 2) ? pr2 : pr3;
                const float ys  = (s == 0) ? yc.x : (s == 1) ? yc.y : (s == 2) ? yc.z : yc.w;
                const float ms  = (s == 0) ? mc.x : (s == 1) ? mc.y : (s == 2) ? mc.z : mc.w;
                ll += (ys * __logf(prs + 1e-10f)
                     + (1.0f - ys) * __logf(1.0f - prs + 1e-10f)) * ms;
            }

            Lc0 = Ln0; Lc1 = Ln1; Lc2 = Ln2; Lc3 = Ln3;
            Lc4 = Ln4; Lc5 = Ln5; Lc6 = Ln6; Lc7 = Ln7;
            sc = snn; yc = ynn; mc = mnn;
        }

        // full-wave ll reduce, one atomic per wave per rep
        #pragma unroll
        for (int off = 1; off < 64; off <<= 1) ll += __shfl_xor(ll, off, 64);
        if ((threadIdx.x & 63) == 0) atomicAdd(llp, ll);
    }
#undef STEP
}

// ---------------------------------------------------------------------------
extern "C" void kernel_launch(void* const* d_in, const int* in_sizes, int n_in,
                              void* d_out, int out_size, void* d_ws, size_t ws_size,
                              hipStream_t stream) {
    const float* S     = (const float*)d_in[0];
    const float* L     = (const float*)d_in[1];
    const float* C     = (const float*)d_in[2];
    const float* Y     = (const float*)d_in[3];
    const float* M     = (const float*)d_in[4];
    const float* psi   = (const float*)d_in[5];
    const float* gA    = (const float*)d_in[6];
    const float* wgd   = (const float*)d_in[7];
    const float* wgs   = (const float*)d_in[8];
    const float* lsz   = (const float*)d_in[9];
    const float* b0    = (const float*)d_in[10];
    const float* bZ    = (const float*)d_in[11];
    const float* bbins = (const float*)d_in[12];
    const float* wbd   = (const float*)d_in[13];
    const float* wbs   = (const float*)d_in[14];
    const float* bT    = (const float*)d_in[15];

    const int NT    = in_sizes[0];        // N*T = 4194304
    const int n_seq = NT / T_LEN;         // 32768

    // real outputs
    float* zf = (float*)d_out;
    float* zv = zf + NT;
    float* ll = zf + 2 * (size_t)NT;

    // dummy outputs (d_ws)
    float* zf_d = (float*)d_ws;
    float* zv_d = zf_d + NT;
    float* ll_d = zf_d + 2 * (size_t)NT;

    hipMemsetAsync((void*)ll, 0, sizeof(float), stream);
    hipMemsetAsync((void*)ll_d, 0, sizeof(float), stream);

    const int threads = 256;
    const int blocks  = (n_seq * 4) / threads;   // 512

    k_fused3<<<blocks, threads, 0, stream>>>(
        reinterpret_cast<const float4*>(S),
        reinterpret_cast<const float4*>(Y),
        reinterpret_cast<const float4*>(M),
        reinterpret_cast<const float4*>(C),
        reinterpret_cast<const float4*>(L),
        reinterpret_cast<const float4*>(wgd),
        reinterpret_cast<const float4*>(wbd),
        reinterpret_cast<const float4*>(wgs),
        reinterpret_cast<const float4*>(wbs),
        psi, gA, lsz, b0, bZ, bbins, bT,
        zf, zv, ll,
        zf_d, zv_d, ll_d);
}

// Round 11
// 168.512 us; speedup vs baseline: 2.6741x; 2.6741x over previous
//
#include <hip/hip_runtime.h>

#define T_LEN 128
#define NB_BINS 15

// ---------------------------------------------------------------------------
// Fused kernel, 8 lanes per sequence (16 waves/CU), depth-2 chunk prefetch
// (3 rotating register buffers, counted vmcnt waits -> never drains),
// full-64B-line nontemporal output writes.
//  - lane j owns L elements [4j,4j+4): one L-load instr = full 128B row/seq
//  - chunk = 4 timesteps: 4 L rows + S/Y/M float4 broadcasts (7 loads)
//  - all 8 lanes run the scan redundantly; lane j stashes steps {2j,2j+1}
//    of each 16-step quad as float2 -> group writes 64B contiguous
//  - ll: lane j adds log terms only for its stashed steps (each step once)
// ---------------------------------------------------------------------------
__global__ __launch_bounds__(256, 4) void k_fused8(
    const float4* __restrict__ S4,
    const float4* __restrict__ Y4,
    const float4* __restrict__ M4,
    const float4* __restrict__ C4,
    const float4* __restrict__ L4,
    const float4* __restrict__ wgd4,
    const float4* __restrict__ wbd4,
    const float4* __restrict__ wgs4,
    const float4* __restrict__ wbs4,
    const float*  __restrict__ p_psi,
    const float*  __restrict__ p_gA,
    const float*  __restrict__ p_lsz,
    const float*  __restrict__ p_b0,
    const float*  __restrict__ p_bZ,
    const float*  __restrict__ p_bbins,
    const float*  __restrict__ p_bT,
    float* __restrict__ zf,
    float* __restrict__ zv,
    float*  __restrict__ ll_out)
{
    __shared__ float sbins[NB_BINS];
    if (threadIdx.x < NB_BINS) sbins[threadIdx.x] = p_bbins[threadIdx.x];
    __syncthreads();

    const int gtid = blockIdx.x * blockDim.x + threadIdx.x;
    const int n = gtid >> 3;     // sequence index
    const int j = gtid & 7;      // sublane within 8-lane group

    // lane j owns L row elements [4j, 4j+4)
    const float4 wg = wgd4[j];
    const float4 wb = wbd4[j];

    const float psi  = p_psi[0];
    const float gA   = p_gA[0];
    const float e    = __expf(p_lsz[0]);
    const float sig2 = e * e;
    const float b0   = p_b0[0];
    const float bZ   = p_bZ[0];
    const float bT30 = p_bT[0] * (1.0f / 30.0f);
    const float psi2 = psi * psi;
    const float bZ2  = bZ * bZ;

    // static dots: lanes j and j+4 duplicate element-quad j&3; xor 1,2 reduce
    float gs, bs;
    {
        const float4 c  = C4[n * 4 + (j & 3)];
        const float4 wgsv = wgs4[j & 3];
        const float4 wbsv = wbs4[j & 3];
        gs = c.x * wgsv.x + c.y * wgsv.y + c.z * wgsv.z + c.w * wgsv.w;
        bs = c.x * wbsv.x + c.y * wbsv.y + c.z * wbsv.z + c.w * wbsv.w;
        gs += __shfl_xor(gs, 1, 64); gs += __shfl_xor(gs, 2, 64);
        bs += __shfl_xor(bs, 1, 64); bs += __shfl_xor(bs, 2, 64);
    }

    const size_t lb = (size_t)n * 1024;   // L float4 base (16KB/seq)
    const int    sb = n * 32;             // S/Y/M float4 chunk base

    float zm = 0.0f, zvv = 1.0f, ll = 0.0f;
    float pmS0 = 0.f, pmS1 = 0.f, pvS0 = 0.f, pvS1 = 0.f;

#define LOAD(P, c) do {                                                       \
        const size_t rb = lb + (size_t)(c) * 32 + j;                          \
        P##0 = L4[rb];      P##1 = L4[rb + 8];                                \
        P##2 = L4[rb + 16]; P##3 = L4[rb + 24];                               \
        P##s = S4[sb + (c)]; P##y = Y4[sb + (c)]; P##m = M4[sb + (c)];        \
    } while (0)

#define STEP(i, Lv, SS, YY, MM, c) do {                                       \
        const float s_v = (SS), y_v = (YY), m_v = (MM);                       \
        float g   = Lv.x*wg.x + Lv.y*wg.y + Lv.z*wg.z + Lv.w*wg.w;            \
        float bdv = Lv.x*wb.x + Lv.y*wb.y + Lv.z*wb.z + Lv.w*wb.w;            \
        g   += __shfl_xor(g,   1, 64); g   += __shfl_xor(g,   2, 64);         \
        g   += __shfl_xor(g,   4, 64);                                        \
        bdv += __shfl_xor(bdv, 1, 64); bdv += __shfl_xor(bdv, 2, 64);         \
        bdv += __shfl_xor(bdv, 4, 64);                                        \
        int cnt = (int)fmaxf(0.0f, fminf(14.0f,                               \
                      ceilf(fmaf(s_v, 3.0f, 7.5f)) - 1.0f));                  \
        const float be   = sbins[cnt];                                        \
        const float zpm  = psi * zm + gA * s_v + g + gs;                      \
        const float zpv  = psi2 * zvv + sig2;                                 \
        float logit = b0 + bZ * zpm + be + bdv + bs                           \
                    + bT30 * (float)(4 * (c) + (i));                          \
        logit = fminf(fmaxf(logit, -20.0f), 20.0f);                           \
        const float prob = __builtin_amdgcn_rcpf(1.0f + __expf(-logit));      \
        const float grad = (y_v - prob) * bZ * m_v;                           \
        const float hess = bZ2 * prob * (1.0f - prob) * m_v + 1e-6f;          \
        const float pvv  = __builtin_amdgcn_rcpf(                             \
                   __builtin_amdgcn_rcpf(zpv + 1e-8f) + hess);                \
        const float pmm  = zpm + pvv * grad;                                  \
        zm = pmm; zvv = pvv;                                                  \
        /* lane owner = ((c&3)<<1) + (i>>1) stashes slot i&1 and adds ll */   \
        if (j == (((c) & 3) * 2 + ((i) >> 1))) {                              \
            if ((i) & 1) { pmS1 = pmm; pvS1 = pvv; }                          \
            else         { pmS0 = pmm; pvS0 = pvv; }                          \
            ll += (y_v * __logf(prob + 1e-10f)                                \
                 + (1.0f - y_v) * __logf(1.0f - prob + 1e-10f)) * m_v;        \
        }                                                                     \
    } while (0)

#define COMP(P, c) do {                                                       \
        STEP(0, P##0, P##s.x, P##y.x, P##m.x, c);                             \
        STEP(1, P##1, P##s.y, P##y.y, P##m.y, c);                             \
        STEP(2, P##2, P##s.z, P##y.z, P##m.z, c);                             \
        STEP(3, P##3, P##s.w, P##y.w, P##m.w, c);                             \
        if (((c) & 3) == 3) {  /* quad complete: 64B-line group write */      \
            const size_t ob = (size_t)n * 128 + ((c) >> 2) * 16 + j * 2;      \
            __builtin_nontemporal_store(pmS0, &zf[ob]);                       \
            __builtin_nontemporal_store(pmS1, &zf[ob + 1]);                   \
            __builtin_nontemporal_store(pvS0, &zv[ob]);                       \
            __builtin_nontemporal_store(pvS1, &zv[ob + 1]);                   \
        }                                                                     \
    } while (0)

    float4 A0, A1, A2, A3, As, Ay, Am;
    float4 B0, B1, B2, B3, Bs, By, Bm;
    float4 D0, D1, D2, D3, Ds, Dy, Dm;

    LOAD(A, 0);
    LOAD(B, 1);

    // 32 chunks; rotate A,B,D with depth-2 prefetch (loads never exceed 31)
    for (int k = 0; k < 30; k += 3) {
        LOAD(D, k + 2); COMP(A, k);
        LOAD(A, k + 3); COMP(B, k + 1);
        LOAD(B, k + 4); COMP(D, k + 2);
    }
    COMP(A, 30);
    COMP(B, 31);

#undef COMP
#undef STEP
#undef LOAD

    // each (seq, step) ll term counted exactly once -> full-wave reduce
    #pragma unroll
    for (int off = 1; off < 64; off <<= 1) ll += __shfl_xor(ll, off, 64);
    if ((threadIdx.x & 63) == 0) atomicAdd(ll_out, ll);
}

// ---------------------------------------------------------------------------
extern "C" void kernel_launch(void* const* d_in, const int* in_sizes, int n_in,
                              void* d_out, int out_size, void* d_ws, size_t ws_size,
                              hipStream_t stream) {
    const float* S     = (const float*)d_in[0];
    const float* L     = (const float*)d_in[1];
    const float* C     = (const float*)d_in[2];
    const float* Y     = (const float*)d_in[3];
    const float* M     = (const float*)d_in[4];
    const float* psi   = (const float*)d_in[5];
    const float* gA    = (const float*)d_in[6];
    const float* wgd   = (const float*)d_in[7];
    const float* wgs   = (const float*)d_in[8];
    const float* lsz   = (const float*)d_in[9];
    const float* b0    = (const float*)d_in[10];
    const float* bZ    = (const float*)d_in[11];
    const float* bbins = (const float*)d_in[12];
    const float* wbd   = (const float*)d_in[13];
    const float* wbs   = (const float*)d_in[14];
    const float* bT    = (const float*)d_in[15];

    const int NT    = in_sizes[0];        // N*T = 4194304
    const int n_seq = NT / T_LEN;         // 32768

    float* zf = (float*)d_out;
    float* zv = zf + NT;
    float* ll = zf + 2 * (size_t)NT;

    hipMemsetAsync((void*)ll, 0, sizeof(float), stream);

    const int threads = 256;
    const int blocks  = (n_seq * 8) / threads;   // 1024 blocks, 4096 waves
    k_fused8<<<blocks, threads, 0, stream>>>(
        reinterpret_cast<const float4*>(S),
        reinterpret_cast<const float4*>(Y),
        reinterpret_cast<const float4*>(M),
        reinterpret_cast<const float4*>(C),
        reinterpret_cast<const float4*>(L),
        reinterpret_cast<const float4*>(wgd),
        reinterpret_cast<const float4*>(wbd),
        reinterpret_cast<const float4*>(wgs),
        reinterpret_cast<const float4*>(wbs),
        psi, gA, lsz, b0, bZ, bbins, bT,
        zf, zv, ll);
}